// Round 3
// baseline (526.265 us; speedup 1.0000x reference)
//
#include <hip/hip_runtime.h>
#include <stdint.h>

typedef unsigned int uint;
typedef unsigned short ushort;

#define NNODES 100000
#define NPAD   100096          // NNODES rounded up to 128
#define NEDGES 1600000
#define RCONST 400
#define CAP    64              // fixed per-node edge capacity (Poisson(16): P(deg>63)~8e-20)

// atomic-free binned CSR build
#define NBKT   196             // ceil(NPAD / 512)
#define NBLK_A 512             // binfill blocks
#define EPB    3125            // NEDGES / NBLK_A, exact
#define RUNCAP 64              // per-(block,bucket) slot capacity; mean 16, P(>64)~2e-18

typedef __attribute__((ext_vector_type(8))) short short8;
typedef __attribute__((ext_vector_type(4))) float f32x4;

__device__ __forceinline__ float bflo(uint u){ union{uint i;float f;}c; c.i=u<<16; return c.f; }
__device__ __forceinline__ float bfhi(uint u){ union{uint i;float f;}c; c.i=u&0xFFFF0000u; return c.f; }
__device__ __forceinline__ ushort f2bf(float f){ union{uint i;float ff;}c; c.ff=f; uint u=c.i;
    return (ushort)((u + 0x7FFFu + ((u>>16)&1u))>>16); }
__device__ __forceinline__ uint pack2(float lo, float hi){
    return (uint)f2bf(lo) | ((uint)f2bf(hi)<<16); }

// ---------------- phase A: bin edges by coarse dst bucket, atomic-free ----------------

__global__ __launch_bounds__(256) void binfill_kernel(const int* __restrict__ edges,
                                                      int* __restrict__ runcnt,   // [NBLK_A][NBKT]
                                                      uint* __restrict__ binned) { // [NBKT][NBLK_A][RUNCAP]
    __shared__ int pos[NBKT];
    int blk = blockIdx.x, tid = threadIdx.x;
    for (int i = tid; i < NBKT; i += 256) pos[i] = 0;
    __syncthreads();
    int start = blk * EPB;
    for (int i = tid; i < EPB; i += 256) {
        int e = start + i;
        int src = edges[e * 3];
        int rel = edges[e * 3 + 1];
        int dst = edges[e * 3 + 2];
        int bkt = (rel >= RCONST) + (rel >= 2 * RCONST);
        int b = dst >> 9, off = dst & 511;
        int p = atomicAdd(&pos[b], 1);         // LDS atomic
        if (p < RUNCAP)
            binned[((size_t)b * NBLK_A + blk) * RUNCAP + p] =
                (uint)src | ((uint)bkt << 17) | ((uint)off << 19);
    }
    __syncthreads();
    for (int i = tid; i < NBKT; i += 256)
        runcnt[blk * NBKT + i] = min(pos[i], RUNCAP);
}

// ---------------- phase B: per-bucket fine scatter into elist, LDS positions ----------------

__global__ __launch_bounds__(256) void scatter_kernel(const uint* __restrict__ binned,
                                                      const int* __restrict__ runcnt,
                                                      int* __restrict__ cnt,
                                                      int* __restrict__ elist) {
    __shared__ int c512[512];
    int b = blockIdx.x, tid = threadIdx.x;
    int base = b << 9;
    for (int i = tid; i < 512; i += 256) c512[i] = 0;
    __syncthreads();
    #pragma unroll
    for (int rr = 0; rr < 2; ++rr) {
        int r = tid * 2 + rr;                  // each thread drains 2 runs
        int n = runcnt[r * NBKT + b];
        const uint* p = binned + ((size_t)b * NBLK_A + r) * RUNCAP;
        for (int i = 0; i < n; ++i) {
            uint e = p[i];
            int off = (int)(e >> 19);
            int q = atomicAdd(&c512[off], 1);  // LDS atomic
            if (q < CAP) elist[(size_t)(base + off) * CAP + q] = (int)(e & 0x7FFFFu);
        }
    }
    __syncthreads();
    for (int i = tid; i < 512; i += 256) {
        int node = base + i;
        if (node < NPAD) cnt[node] = min(c512[i], CAP);
    }
}

// ---------------- conversions ----------------

__global__ __launch_bounds__(256) void convx_kernel(const float* __restrict__ x,
                                                    uint* __restrict__ xb) {
    size_t i = (size_t)blockIdx.x * 256 + threadIdx.x;   // pair index
    if (i < (size_t)NNODES * 64) {
        float2 f = *(const float2*)&x[i * 2];
        xb[i] = pack2(f.x, f.y);
    }
}

// Wb[n][k] bf16, k<384: W[k>>7][n][k&127]; k>=384: Ws[n][k-384]
__global__ __launch_bounds__(256) void wconv_kernel(const float* __restrict__ W,
                                                    const float* __restrict__ Ws,
                                                    uint* __restrict__ Wb) {
    int i = blockIdx.x * 256 + threadIdx.x;   // pair index, 128*256
    if (i < 128 * 256) {
        int n = i >> 8, kp = i & 255, k = kp * 2;
        float v0, v1;
        if (k < 384) {
            int r = k >> 7, kk = k & 127;
            const float* p = W + r * 16384 + n * 128 + kk;
            v0 = p[0]; v1 = p[1];
        } else {
            const float* p = Ws + n * 128 + (k - 384);
            v0 = p[0]; v1 = p[1];
        }
        Wb[i] = pack2(v0, v1);
    }
}

// ---------------- gather: one wave per node ----------------

__global__ __launch_bounds__(256) void gather_kernel(
    const uint* __restrict__ xb,       // [NPAD][64] bf16-pairs
    const int* __restrict__ cnt,       // per-node degree (clamped to CAP)
    const int* __restrict__ elist,     // [NPAD][CAP] entries src|bkt<<17
    uint* __restrict__ Ab,             // [NPAD][192] bf16-pairs
    float4* __restrict__ cnts) {       // per-node (c0,c1,c2,inv)
    int w = threadIdx.x >> 6, lane = threadIdx.x & 63;
    int node = blockIdx.x * 4 + w;     // grid = NNODES/4 exactly
    int deg = min(cnt[node], CAP);
    float inv = 1.0f / fmaxf((float)deg, 1.0f);

    float a0l = 0.f, a0h = 0.f, a1l = 0.f, a1h = 0.f, a2l = 0.f, a2h = 0.f;
    int c0 = 0, c1 = 0, c2 = 0;

    for (int base = 0; base < deg; base += 64) {
        int m = min(64, deg - base);
        int ve = 0;
        if (lane < m) ve = elist[(size_t)node * CAP + base + lane];

        int j = 0;
        for (; j + 4 <= m; j += 4) {
            int e0 = __builtin_amdgcn_readlane(ve, j);
            int e1 = __builtin_amdgcn_readlane(ve, j + 1);
            int e2 = __builtin_amdgcn_readlane(ve, j + 2);
            int e3 = __builtin_amdgcn_readlane(ve, j + 3);
            int s0 = e0 & 0x1FFFF, k0 = e0 >> 17;
            int s1 = e1 & 0x1FFFF, k1 = e1 >> 17;
            int s2 = e2 & 0x1FFFF, k2 = e2 >> 17;
            int s3 = e3 & 0x1FFFF, k3 = e3 >> 17;
            uint u0 = xb[((size_t)s0 << 6) + lane];
            uint u1 = xb[((size_t)s1 << 6) + lane];
            uint u2 = xb[((size_t)s2 << 6) + lane];
            uint u3 = xb[((size_t)s3 << 6) + lane];

            float q00 = (k0 == 0) ? 1.f : 0.f, q01 = (k0 == 1) ? 1.f : 0.f, q02 = (k0 == 2) ? 1.f : 0.f;
            float q10 = (k1 == 0) ? 1.f : 0.f, q11 = (k1 == 1) ? 1.f : 0.f, q12 = (k1 == 2) ? 1.f : 0.f;
            float q20 = (k2 == 0) ? 1.f : 0.f, q21 = (k2 == 1) ? 1.f : 0.f, q22 = (k2 == 2) ? 1.f : 0.f;
            float q30 = (k3 == 0) ? 1.f : 0.f, q31 = (k3 == 1) ? 1.f : 0.f, q32 = (k3 == 2) ? 1.f : 0.f;
            c0 += (k0 == 0) + (k1 == 0) + (k2 == 0) + (k3 == 0);
            c1 += (k0 == 1) + (k1 == 1) + (k2 == 1) + (k3 == 1);
            c2 += (k0 == 2) + (k1 == 2) + (k2 == 2) + (k3 == 2);

            float f0l = bflo(u0), f0h = bfhi(u0);
            float f1l = bflo(u1), f1h = bfhi(u1);
            float f2l = bflo(u2), f2h = bfhi(u2);
            float f3l = bflo(u3), f3h = bfhi(u3);

            a0l = fmaf(q00, f0l, a0l); a1l = fmaf(q01, f0l, a1l); a2l = fmaf(q02, f0l, a2l);
            a0h = fmaf(q00, f0h, a0h); a1h = fmaf(q01, f0h, a1h); a2h = fmaf(q02, f0h, a2h);
            a0l = fmaf(q10, f1l, a0l); a1l = fmaf(q11, f1l, a1l); a2l = fmaf(q12, f1l, a2l);
            a0h = fmaf(q10, f1h, a0h); a1h = fmaf(q11, f1h, a1h); a2h = fmaf(q12, f1h, a2h);
            a0l = fmaf(q20, f2l, a0l); a1l = fmaf(q21, f2l, a1l); a2l = fmaf(q22, f2l, a2l);
            a0h = fmaf(q20, f2h, a0h); a1h = fmaf(q21, f2h, a1h); a2h = fmaf(q22, f2h, a2h);
            a0l = fmaf(q30, f3l, a0l); a1l = fmaf(q31, f3l, a1l); a2l = fmaf(q32, f3l, a2l);
            a0h = fmaf(q30, f3h, a0h); a1h = fmaf(q31, f3h, a1h); a2h = fmaf(q32, f3h, a2h);
        }
        for (; j < m; ++j) {
            int ee = __builtin_amdgcn_readlane(ve, j);
            int s = ee & 0x1FFFF, k = ee >> 17;
            uint u = xb[((size_t)s << 6) + lane];
            float q0 = (k == 0) ? 1.f : 0.f;
            float q1 = (k == 1) ? 1.f : 0.f;
            float q2 = (k == 2) ? 1.f : 0.f;
            c0 += (k == 0); c1 += (k == 1); c2 += (k == 2);
            float fl = bflo(u), fh = bfhi(u);
            a0l = fmaf(q0, fl, a0l); a1l = fmaf(q1, fl, a1l); a2l = fmaf(q2, fl, a2l);
            a0h = fmaf(q0, fh, a0h); a1h = fmaf(q1, fh, a1h); a2h = fmaf(q2, fh, a2h);
        }
    }

    size_t ab = (size_t)node * 192 + lane;
    Ab[ab]       = pack2(a0l * inv, a0h * inv);
    Ab[ab + 64]  = pack2(a1l * inv, a1h * inv);
    Ab[ab + 128] = pack2(a2l * inv, a2h * inv);
    if (lane == 0) {
        float4 v; v.x = (float)c0; v.y = (float)c1; v.z = (float)c2; v.w = inv;
        cnts[node] = v;
    }
}

// ---------------- MFMA GEMM + fused epilogue, no LDS staging ----------------
// 512 threads = 8 waves: wm = w>>2 (row half), wn = w&3 (col quarter).
// Per wave: 64 rows x 32 cols, acc = 12 frags (48 f32) + skip 8 frags.
// A/B fragments are 16B short8 loads straight from global (L1/L2-served);
// zero barriers in the K loop, no LDS tile, no bank conflicts.
// LayerNorm: in-register row partials -> 16-lane shfl reduce -> 5KB LDS
// cross-wave combine -> normalize in registers -> direct store.

template<bool OUT_BF16>
__global__ __launch_bounds__(512, 2) void gemm_kernel(
    const ushort* __restrict__ Ab,     // [NPAD][384]
    const ushort* __restrict__ xb,     // [NPAD][128]
    const ushort* __restrict__ Wb,     // [128][512]
    const float* __restrict__ bia,     // [3][128]
    const float* __restrict__ bs,
    const float* __restrict__ g,
    const float* __restrict__ be,
    const float4* __restrict__ cnts,   // [NPAD] (c0,c1,c2,inv)
    void* __restrict__ out) {
    __shared__ float sS1[4][128], sS2[4][128];
    __shared__ float sMean[128], sRstd[128];

    int tid = threadIdx.x;
    int w = tid >> 6, lane = tid & 63;
    int wm = w >> 2, wn = w & 3;
    int quad = lane >> 4, l15 = lane & 15;
    int node0 = blockIdx.x * 128;

    f32x4 accm[4][2], accq[4][2];
    f32x4 zero = {0.f, 0.f, 0.f, 0.f};
    #pragma unroll
    for (int i = 0; i < 4; ++i)
        #pragma unroll
        for (int j = 0; j < 2; ++j) { accm[i][j] = zero; accq[i][j] = zero; }

    const ushort* pA = Ab + (size_t)(node0 + wm * 64 + l15) * 384 + quad * 8;
    const ushort* pX = xb + (size_t)(node0 + wm * 64 + l15) * 128 + quad * 8;
    const ushort* pB = Wb + (size_t)(wn * 32 + l15) * 512 + quad * 8;

    // K = 0..383: message GEMM (A = Ab)
    #pragma unroll
    for (int kc = 0; kc < 3; ++kc) {
        #pragma unroll
        for (int ks = 0; ks < 4; ++ks) {
            int ko = kc * 128 + ks * 32;
            short8 aF[4], bF[2];
            #pragma unroll
            for (int mt = 0; mt < 4; ++mt)
                aF[mt] = *(const short8*)(pA + (size_t)mt * 16 * 384 + ko);
            #pragma unroll
            for (int nt = 0; nt < 2; ++nt)
                bF[nt] = *(const short8*)(pB + (size_t)nt * 16 * 512 + ko);
            #pragma unroll
            for (int mt = 0; mt < 4; ++mt)
                #pragma unroll
                for (int nt = 0; nt < 2; ++nt)
                    accm[mt][nt] = __builtin_amdgcn_mfma_f32_16x16x32_bf16(
                        aF[mt], bF[nt], accm[mt][nt], 0, 0, 0);
        }
    }
    // K = 384..511: skip GEMM (A = xb)
    #pragma unroll
    for (int ks = 0; ks < 4; ++ks) {
        int xo = ks * 32, ko = 384 + ks * 32;
        short8 aF[4], bF[2];
        #pragma unroll
        for (int mt = 0; mt < 4; ++mt)
            aF[mt] = *(const short8*)(pX + (size_t)mt * 16 * 128 + xo);
        #pragma unroll
        for (int nt = 0; nt < 2; ++nt)
            bF[nt] = *(const short8*)(pB + (size_t)nt * 16 * 512 + ko);
        #pragma unroll
        for (int mt = 0; mt < 4; ++mt)
            #pragma unroll
            for (int nt = 0; nt < 2; ++nt)
                accq[mt][nt] = __builtin_amdgcn_mfma_f32_16x16x32_bf16(
                    aF[mt], bF[nt], accq[mt][nt], 0, 0, 0);
    }

    // epilogue: v = relu(accm + bias_msg) + accq + bs, then LN
    int nl0 = wn * 32 + l15;
    float pb0[2], pb1[2], pb2[2], pbs[2], pg[2], pbe[2];
    #pragma unroll
    for (int nt = 0; nt < 2; ++nt) {
        int nl = nl0 + nt * 16;
        pb0[nt] = bia[nl]; pb1[nt] = bia[128 + nl]; pb2[nt] = bia[256 + nl];
        pbs[nt] = bs[nl];  pg[nt] = g[nl];          pbe[nt] = be[nl];
    }
    #pragma unroll
    for (int mt = 0; mt < 4; ++mt) {
        #pragma unroll
        for (int r = 0; r < 4; ++r) {
            int ml = wm * 64 + mt * 16 + quad * 4 + r;
            float4 c4 = cnts[node0 + ml];
            float s1 = 0.f, s2 = 0.f;
            #pragma unroll
            for (int nt = 0; nt < 2; ++nt) {
                float bd = (c4.x * pb0[nt] + c4.y * pb1[nt] + c4.z * pb2[nt]) * c4.w;
                float v = fmaxf(accm[mt][nt][r] + bd, 0.f) + accq[mt][nt][r] + pbs[nt];
                accm[mt][nt][r] = v;
                s1 += v; s2 += v * v;
            }
            #pragma unroll
            for (int mask = 1; mask < 16; mask <<= 1) {
                s1 += __shfl_xor(s1, mask);
                s2 += __shfl_xor(s2, mask);
            }
            if (l15 == 0) { sS1[wn][ml] = s1; sS2[wn][ml] = s2; }
        }
    }
    __syncthreads();
    if (tid < 128) {
        float s1 = sS1[0][tid] + sS1[1][tid] + sS1[2][tid] + sS1[3][tid];
        float s2 = sS2[0][tid] + sS2[1][tid] + sS2[2][tid] + sS2[3][tid];
        float mean = s1 * (1.f / 128.f);
        float var = s2 * (1.f / 128.f) - mean * mean;
        sMean[tid] = mean;
        sRstd[tid] = rsqrtf(var + 1e-5f);
    }
    __syncthreads();
    #pragma unroll
    for (int mt = 0; mt < 4; ++mt) {
        #pragma unroll
        for (int r = 0; r < 4; ++r) {
            int ml = wm * 64 + mt * 16 + quad * 4 + r;
            int node = node0 + ml;
            float mn = sMean[ml], rs = sRstd[ml];
            #pragma unroll
            for (int nt = 0; nt < 2; ++nt) {
                float v = (accm[mt][nt][r] - mn) * rs * pg[nt] + pbe[nt];
                if (OUT_BF16) {
                    float vh = __shfl_xor(v, 1);
                    if (!(l15 & 1) && node < NNODES) {
                        uint* o = (uint*)out;
                        o[(size_t)node * 64 + wn * 16 + nt * 8 + (l15 >> 1)] = pack2(v, vh);
                    }
                } else {
                    if (node < NNODES) {
                        float* o = (float*)out;
                        o[(size_t)node * 128 + nl0 + nt * 16] = v;
                    }
                }
            }
        }
    }
}

// ---------------- launch ----------------

extern "C" void kernel_launch(void* const* d_in, const int* in_sizes, int n_in,
                              void* d_out, int out_size, void* d_ws, size_t ws_size,
                              hipStream_t stream) {
    (void)in_sizes; (void)n_in; (void)out_size; (void)ws_size;

    const int*   edges = (const int*)d_in[0];
    const float* xemb  = (const float*)d_in[1];
    const float* W1  = (const float*)d_in[2];
    const float* b1  = (const float*)d_in[3];
    const float* Ws1 = (const float*)d_in[4];
    const float* bs1 = (const float*)d_in[5];
    const float* g1  = (const float*)d_in[6];
    const float* be1 = (const float*)d_in[7];
    const float* W2  = (const float*)d_in[8];
    const float* b2  = (const float*)d_in[9];
    const float* Ws2 = (const float*)d_in[10];
    const float* bs2 = (const float*)d_in[11];
    const float* g2  = (const float*)d_in[12];
    const float* be2 = (const float*)d_in[13];

    char* ws = (char*)d_ws;
    auto take = [&](size_t bytes) {
        char* p = ws;
        ws += (bytes + 255) & ~(size_t)255;
        return p;
    };
    int*    cnt    = (int*)take((size_t)NPAD * 4);
    int*    elist  = (int*)take((size_t)NPAD * CAP * 4);
    float4* cnts   = (float4*)take((size_t)NPAD * 16);
    uint*   xb0    = (uint*)take((size_t)NPAD * 128 * 2);
    uint*   xb1    = (uint*)take((size_t)NPAD * 128 * 2);
    uint*   Ab     = (uint*)take((size_t)NPAD * 384 * 2);
    uint*   Wb1    = (uint*)take((size_t)128 * 512 * 2);
    uint*   Wb2    = (uint*)take((size_t)128 * 512 * 2);
    int*    runcnt = (int*)take((size_t)NBLK_A * NBKT * 4);
    uint*   binned = (uint*)take((size_t)NBKT * NBLK_A * RUNCAP * 4);

    binfill_kernel<<<NBLK_A, 256, 0, stream>>>(edges, runcnt, binned);
    scatter_kernel<<<NBKT, 256, 0, stream>>>(binned, runcnt, cnt, elist);

    convx_kernel<<<(NNODES * 64) / 256, 256, 0, stream>>>(xemb, xb0);
    wconv_kernel<<<128, 256, 0, stream>>>(W1, Ws1, Wb1);
    wconv_kernel<<<128, 256, 0, stream>>>(W2, Ws2, Wb2);

    gather_kernel<<<NNODES / 4, 256, 0, stream>>>(xb0, cnt, elist, Ab, cnts);
    gemm_kernel<true><<<(NNODES + 127) / 128, 512, 0, stream>>>(
        (const ushort*)Ab, (const ushort*)xb0, (const ushort*)Wb1,
        b1, bs1, g1, be1, cnts, xb1);

    gather_kernel<<<NNODES / 4, 256, 0, stream>>>(xb1, cnt, elist, Ab, cnts);
    gemm_kernel<false><<<(NNODES + 127) / 128, 512, 0, stream>>>(
        (const ushort*)Ab, (const ushort*)xb1, (const ushort*)Wb2,
        b2, bs2, g2, be2, cnts, d_out);
}

// Round 4
// 402.417 us; speedup vs baseline: 1.3078x; 1.3078x over previous
//
#include <hip/hip_runtime.h>
#include <stdint.h>

typedef unsigned int uint;
typedef unsigned short ushort;

#define NNODES 100000
#define NPAD   100096          // NNODES rounded up to 128
#define NEDGES 1600000
#define RCONST 400
#define CAP    64              // fixed per-node edge capacity (Poisson(16): P(deg>63)~8e-20)

// atomic-free binned CSR build
#define NBKT   196             // ceil(NPAD / 512)
#define NBLK_A 512             // binfill blocks
#define EPB    3125            // NEDGES / NBLK_A, exact
#define RUNCAP 64              // per-(block,bucket) slot capacity; mean 16, P(>64)~2e-18

typedef __attribute__((ext_vector_type(8))) short short8;
typedef __attribute__((ext_vector_type(4))) float f32x4;

__device__ __forceinline__ float bflo(uint u){ union{uint i;float f;}c; c.i=u<<16; return c.f; }
__device__ __forceinline__ float bfhi(uint u){ union{uint i;float f;}c; c.i=u&0xFFFF0000u; return c.f; }
__device__ __forceinline__ ushort f2bf(float f){ union{uint i;float ff;}c; c.ff=f; uint u=c.i;
    return (ushort)((u + 0x7FFFu + ((u>>16)&1u))>>16); }
__device__ __forceinline__ uint pack2(float lo, float hi){
    return (uint)f2bf(lo) | ((uint)f2bf(hi)<<16); }

// ---------------- phase A: bin edges by coarse dst bucket, atomic-free ----------------

__global__ __launch_bounds__(256) void binfill_kernel(const int* __restrict__ edges,
                                                      int* __restrict__ runcnt,   // [NBLK_A][NBKT]
                                                      uint* __restrict__ binned) { // [NBKT][NBLK_A][RUNCAP]
    __shared__ int pos[NBKT];
    int blk = blockIdx.x, tid = threadIdx.x;
    for (int i = tid; i < NBKT; i += 256) pos[i] = 0;
    __syncthreads();
    int start = blk * EPB;
    for (int i = tid; i < EPB; i += 256) {
        int e = start + i;
        int src = edges[e * 3];
        int rel = edges[e * 3 + 1];
        int dst = edges[e * 3 + 2];
        int bkt = (rel >= RCONST) + (rel >= 2 * RCONST);
        int b = dst >> 9, off = dst & 511;
        int p = atomicAdd(&pos[b], 1);         // LDS atomic
        if (p < RUNCAP)
            binned[((size_t)b * NBLK_A + blk) * RUNCAP + p] =
                (uint)src | ((uint)bkt << 17) | ((uint)off << 19);
    }
    __syncthreads();
    for (int i = tid; i < NBKT; i += 256)
        runcnt[blk * NBKT + i] = min(pos[i], RUNCAP);
}

// ---------------- phase B: per-bucket fine scatter into elist, LDS positions ----------------

__global__ __launch_bounds__(256) void scatter_kernel(const uint* __restrict__ binned,
                                                      const int* __restrict__ runcnt,
                                                      int* __restrict__ cnt,
                                                      int* __restrict__ elist) {
    __shared__ int c512[512];
    int b = blockIdx.x, tid = threadIdx.x;
    int base = b << 9;
    for (int i = tid; i < 512; i += 256) c512[i] = 0;
    __syncthreads();
    #pragma unroll
    for (int rr = 0; rr < 2; ++rr) {
        int r = tid * 2 + rr;                  // each thread drains 2 runs
        int n = runcnt[r * NBKT + b];
        const uint* p = binned + ((size_t)b * NBLK_A + r) * RUNCAP;
        for (int i = 0; i < n; ++i) {
            uint e = p[i];
            int off = (int)(e >> 19);
            int q = atomicAdd(&c512[off], 1);  // LDS atomic
            if (q < CAP) elist[(size_t)(base + off) * CAP + q] = (int)(e & 0x7FFFFu);
        }
    }
    __syncthreads();
    for (int i = tid; i < 512; i += 256) {
        int node = base + i;
        if (node < NPAD) cnt[node] = min(c512[i], CAP);
    }
}

// ---------------- conversions ----------------

__global__ __launch_bounds__(256) void convx_kernel(const float* __restrict__ x,
                                                    uint* __restrict__ xb) {
    size_t i = (size_t)blockIdx.x * 256 + threadIdx.x;   // pair index
    if (i < (size_t)NNODES * 64) {
        float2 f = *(const float2*)&x[i * 2];
        xb[i] = pack2(f.x, f.y);
    }
}

// Wb[n][k] bf16, k<384: W[k>>7][n][k&127]; k>=384: Ws[n][k-384]
__global__ __launch_bounds__(256) void wconv_kernel(const float* __restrict__ W,
                                                    const float* __restrict__ Ws,
                                                    uint* __restrict__ Wb) {
    int i = blockIdx.x * 256 + threadIdx.x;   // pair index, 128*256
    if (i < 128 * 256) {
        int n = i >> 8, kp = i & 255, k = kp * 2;
        float v0, v1;
        if (k < 384) {
            int r = k >> 7, kk = k & 127;
            const float* p = W + r * 16384 + n * 128 + kk;
            v0 = p[0]; v1 = p[1];
        } else {
            const float* p = Ws + n * 128 + (k - 384);
            v0 = p[0]; v1 = p[1];
        }
        Wb[i] = pack2(v0, v1);
    }
}

// ---------------- gather: one wave per node ----------------

__global__ __launch_bounds__(256) void gather_kernel(
    const uint* __restrict__ xb,       // [NPAD][64] bf16-pairs
    const int* __restrict__ cnt,       // per-node degree (clamped to CAP)
    const int* __restrict__ elist,     // [NPAD][CAP] entries src|bkt<<17
    uint* __restrict__ Ab,             // [NPAD][192] bf16-pairs
    float4* __restrict__ cnts) {       // per-node (c0,c1,c2,inv)
    int w = threadIdx.x >> 6, lane = threadIdx.x & 63;
    int node = blockIdx.x * 4 + w;     // grid = NNODES/4 exactly
    int deg = min(cnt[node], CAP);
    float inv = 1.0f / fmaxf((float)deg, 1.0f);

    float a0l = 0.f, a0h = 0.f, a1l = 0.f, a1h = 0.f, a2l = 0.f, a2h = 0.f;
    int c0 = 0, c1 = 0, c2 = 0;

    for (int base = 0; base < deg; base += 64) {
        int m = min(64, deg - base);
        int ve = 0;
        if (lane < m) ve = elist[(size_t)node * CAP + base + lane];

        int j = 0;
        for (; j + 4 <= m; j += 4) {
            int e0 = __builtin_amdgcn_readlane(ve, j);
            int e1 = __builtin_amdgcn_readlane(ve, j + 1);
            int e2 = __builtin_amdgcn_readlane(ve, j + 2);
            int e3 = __builtin_amdgcn_readlane(ve, j + 3);
            int s0 = e0 & 0x1FFFF, k0 = e0 >> 17;
            int s1 = e1 & 0x1FFFF, k1 = e1 >> 17;
            int s2 = e2 & 0x1FFFF, k2 = e2 >> 17;
            int s3 = e3 & 0x1FFFF, k3 = e3 >> 17;
            uint u0 = xb[((size_t)s0 << 6) + lane];
            uint u1 = xb[((size_t)s1 << 6) + lane];
            uint u2 = xb[((size_t)s2 << 6) + lane];
            uint u3 = xb[((size_t)s3 << 6) + lane];

            float q00 = (k0 == 0) ? 1.f : 0.f, q01 = (k0 == 1) ? 1.f : 0.f, q02 = (k0 == 2) ? 1.f : 0.f;
            float q10 = (k1 == 0) ? 1.f : 0.f, q11 = (k1 == 1) ? 1.f : 0.f, q12 = (k1 == 2) ? 1.f : 0.f;
            float q20 = (k2 == 0) ? 1.f : 0.f, q21 = (k2 == 1) ? 1.f : 0.f, q22 = (k2 == 2) ? 1.f : 0.f;
            float q30 = (k3 == 0) ? 1.f : 0.f, q31 = (k3 == 1) ? 1.f : 0.f, q32 = (k3 == 2) ? 1.f : 0.f;
            c0 += (k0 == 0) + (k1 == 0) + (k2 == 0) + (k3 == 0);
            c1 += (k0 == 1) + (k1 == 1) + (k2 == 1) + (k3 == 1);
            c2 += (k0 == 2) + (k1 == 2) + (k2 == 2) + (k3 == 2);

            float f0l = bflo(u0), f0h = bfhi(u0);
            float f1l = bflo(u1), f1h = bfhi(u1);
            float f2l = bflo(u2), f2h = bfhi(u2);
            float f3l = bflo(u3), f3h = bfhi(u3);

            a0l = fmaf(q00, f0l, a0l); a1l = fmaf(q01, f0l, a1l); a2l = fmaf(q02, f0l, a2l);
            a0h = fmaf(q00, f0h, a0h); a1h = fmaf(q01, f0h, a1h); a2h = fmaf(q02, f0h, a2h);
            a0l = fmaf(q10, f1l, a0l); a1l = fmaf(q11, f1l, a1l); a2l = fmaf(q12, f1l, a2l);
            a0h = fmaf(q10, f1h, a0h); a1h = fmaf(q11, f1h, a1h); a2h = fmaf(q12, f1h, a2h);
            a0l = fmaf(q20, f2l, a0l); a1l = fmaf(q21, f2l, a1l); a2l = fmaf(q22, f2l, a2l);
            a0h = fmaf(q20, f2h, a0h); a1h = fmaf(q21, f2h, a1h); a2h = fmaf(q22, f2h, a2h);
            a0l = fmaf(q30, f3l, a0l); a1l = fmaf(q31, f3l, a1l); a2l = fmaf(q32, f3l, a2l);
            a0h = fmaf(q30, f3h, a0h); a1h = fmaf(q31, f3h, a1h); a2h = fmaf(q32, f3h, a2h);
        }
        for (; j < m; ++j) {
            int ee = __builtin_amdgcn_readlane(ve, j);
            int s = ee & 0x1FFFF, k = ee >> 17;
            uint u = xb[((size_t)s << 6) + lane];
            float q0 = (k == 0) ? 1.f : 0.f;
            float q1 = (k == 1) ? 1.f : 0.f;
            float q2 = (k == 2) ? 1.f : 0.f;
            c0 += (k == 0); c1 += (k == 1); c2 += (k == 2);
            float fl = bflo(u), fh = bfhi(u);
            a0l = fmaf(q0, fl, a0l); a1l = fmaf(q1, fl, a1l); a2l = fmaf(q2, fl, a2l);
            a0h = fmaf(q0, fh, a0h); a1h = fmaf(q1, fh, a1h); a2h = fmaf(q2, fh, a2h);
        }
    }

    size_t ab = (size_t)node * 192 + lane;
    Ab[ab]       = pack2(a0l * inv, a0h * inv);
    Ab[ab + 64]  = pack2(a1l * inv, a1h * inv);
    Ab[ab + 128] = pack2(a2l * inv, a2h * inv);
    if (lane == 0) {
        float4 v; v.x = (float)c0; v.y = (float)c1; v.z = (float)c2; v.w = inv;
        cnts[node] = v;
    }
}

// ---------------- MFMA GEMM + fused epilogue: LDS-staged, pipelined, swizzled ----------------
// 256 threads = 4 waves (1x4): block tile 64(M) x 128(N); wave tile 64 x 32.
// K-chunk 64, single LDS buffer (27 KB -> high residency), register prefetch:
// chunk t+1's global loads are issued BEFORE computing chunk t, so HBM/L3
// latency hides under ds_read+MFMA instead of serializing at the barrier.
// LDS XOR-swizzle (byte ^= (row&7)<<4, T2) -> conflict-free ds_read_b128.
// LayerNorm fully fused, in-register + 2.5 KB cross-wave LDS combine.

template<bool OUT_BF16>
__global__ __launch_bounds__(256, 3) void gemm_kernel(
    const ushort* __restrict__ Ab,     // [NPAD][384]
    const ushort* __restrict__ xb,     // [NPAD][128]
    const ushort* __restrict__ Wb,     // [128][512]
    const float* __restrict__ bia,     // [3][128]
    const float* __restrict__ bs,
    const float* __restrict__ g,
    const float* __restrict__ be,
    const float4* __restrict__ cnts,   // [NPAD] (c0,c1,c2,inv)
    void* __restrict__ out) {
    __shared__ ushort lA[64 * 64];     // 8 KB, swizzled rows of 128 B
    __shared__ ushort lB[128 * 64];    // 16 KB, swizzled rows of 128 B
    __shared__ float sS1[4][64], sS2[4][64];
    __shared__ float sMean[64], sRstd[64];

    int tid = threadIdx.x;
    int w = tid >> 6, lane = tid & 63;
    int wn = w;                        // 4 waves across N
    int quad = lane >> 4, l15 = lane & 15;
    int node0 = blockIdx.x * 64;

    // staging task assignment (fixed per thread)
    int arow = tid >> 2, aseg = tid & 3;        // A: 64 rows x 8 segs(16B), 2 segs/thread
    int brow = tid >> 1, bseg = (tid & 1) * 4;  // B: 128 rows x 8 segs, 4 segs/thread
    uint swzA = (uint)((arow & 7) << 4);
    uint swzB = (uint)((brow & 7) << 4);
    uint swzR = (uint)((l15 & 7) << 4);         // read-side swizzle (row&7 == l15&7)

    const ushort* gA = Ab + (size_t)node0 * 384;
    const ushort* gX = xb + (size_t)node0 * 128;

    f32x4 accm[4][2], accq[4][2];
    f32x4 zero = {0.f, 0.f, 0.f, 0.f};
    #pragma unroll
    for (int i = 0; i < 4; ++i)
        #pragma unroll
        for (int j = 0; j < 2; ++j) { accm[i][j] = zero; accq[i][j] = zero; }

    uint4 ra0, ra1, rb0, rb1, rb2, rb3;
    auto load_chunk = [&](int t) {
        const ushort* srcA; size_t strA;
        if (t < 6) { srcA = gA + t * 64;       strA = 384; }
        else       { srcA = gX + (t - 6) * 64; strA = 128; }
        const ushort* pa = srcA + (size_t)arow * strA + aseg * 8;
        ra0 = *(const uint4*)(pa);
        ra1 = *(const uint4*)(pa + 32);        // seg+4
        const ushort* pb = Wb + t * 64 + (size_t)brow * 512 + bseg * 8;
        rb0 = *(const uint4*)(pb);
        rb1 = *(const uint4*)(pb + 8);
        rb2 = *(const uint4*)(pb + 16);
        rb3 = *(const uint4*)(pb + 24);
    };
    auto compute = [&](f32x4 (&acc)[4][2]) {
        #pragma unroll
        for (int ks = 0; ks < 2; ++ks) {
            short8 aF[4], bF[2];
            #pragma unroll
            for (int mt = 0; mt < 4; ++mt) {
                int row = mt * 16 + l15;
                aF[mt] = *(const short8*)((const char*)lA + row * 128 +
                                          (((uint)(ks * 64 + quad * 16)) ^ swzR));
            }
            #pragma unroll
            for (int nt = 0; nt < 2; ++nt) {
                int row = wn * 32 + nt * 16 + l15;
                bF[nt] = *(const short8*)((const char*)lB + row * 128 +
                                          (((uint)(ks * 64 + quad * 16)) ^ swzR));
            }
            #pragma unroll
            for (int mt = 0; mt < 4; ++mt)
                #pragma unroll
                for (int nt = 0; nt < 2; ++nt)
                    acc[mt][nt] = __builtin_amdgcn_mfma_f32_16x16x32_bf16(
                        aF[mt], bF[nt], acc[mt][nt], 0, 0, 0);
        }
    };

    load_chunk(0);
    for (int t = 0; t < 8; ++t) {
        if (t) __syncthreads();                 // protect LDS from prev chunk's readers
        // regs -> LDS (compiler inserts the vmcnt wait here)
        {
            char* bA = (char*)lA + arow * 128;
            *(uint4*)(bA + (((uint)(aseg * 16)) ^ swzA))       = ra0;
            *(uint4*)(bA + (((uint)((aseg + 4) * 16)) ^ swzA)) = ra1;
            char* bB = (char*)lB + brow * 128;
            *(uint4*)(bB + (((uint)((bseg + 0) * 16)) ^ swzB)) = rb0;
            *(uint4*)(bB + (((uint)((bseg + 1) * 16)) ^ swzB)) = rb1;
            *(uint4*)(bB + (((uint)((bseg + 2) * 16)) ^ swzB)) = rb2;
            *(uint4*)(bB + (((uint)((bseg + 3) * 16)) ^ swzB)) = rb3;
        }
        __syncthreads();
        if (t < 7) load_chunk(t + 1);           // prefetch: latency hides under compute
        if (t < 6) compute(accm); else compute(accq);
    }

    // epilogue: v = relu(accm + bias_msg) + accq + bs, then LN over 128 cols
    int nl0 = wn * 32 + l15;
    float pb0[2], pb1[2], pb2[2], pbs[2], pg[2], pbe[2];
    #pragma unroll
    for (int nt = 0; nt < 2; ++nt) {
        int nl = nl0 + nt * 16;
        pb0[nt] = bia[nl]; pb1[nt] = bia[128 + nl]; pb2[nt] = bia[256 + nl];
        pbs[nt] = bs[nl];  pg[nt] = g[nl];          pbe[nt] = be[nl];
    }
    #pragma unroll
    for (int mt = 0; mt < 4; ++mt) {
        #pragma unroll
        for (int r = 0; r < 4; ++r) {
            int ml = mt * 16 + quad * 4 + r;
            float4 c4 = cnts[node0 + ml];
            float s1 = 0.f, s2 = 0.f;
            #pragma unroll
            for (int nt = 0; nt < 2; ++nt) {
                float bd = (c4.x * pb0[nt] + c4.y * pb1[nt] + c4.z * pb2[nt]) * c4.w;
                float v = fmaxf(accm[mt][nt][r] + bd, 0.f) + accq[mt][nt][r] + pbs[nt];
                accm[mt][nt][r] = v;
                s1 += v; s2 += v * v;
            }
            #pragma unroll
            for (int mask = 1; mask < 16; mask <<= 1) {
                s1 += __shfl_xor(s1, mask);
                s2 += __shfl_xor(s2, mask);
            }
            if (l15 == 0) { sS1[wn][ml] = s1; sS2[wn][ml] = s2; }
        }
    }
    __syncthreads();
    if (tid < 64) {
        float s1 = sS1[0][tid] + sS1[1][tid] + sS1[2][tid] + sS1[3][tid];
        float s2 = sS2[0][tid] + sS2[1][tid] + sS2[2][tid] + sS2[3][tid];
        float mean = s1 * (1.f / 128.f);
        float var = s2 * (1.f / 128.f) - mean * mean;
        sMean[tid] = mean;
        sRstd[tid] = rsqrtf(var + 1e-5f);
    }
    __syncthreads();
    #pragma unroll
    for (int mt = 0; mt < 4; ++mt) {
        #pragma unroll
        for (int r = 0; r < 4; ++r) {
            int ml = mt * 16 + quad * 4 + r;
            int node = node0 + ml;
            float mn = sMean[ml], rs = sRstd[ml];
            #pragma unroll
            for (int nt = 0; nt < 2; ++nt) {
                float v = (accm[mt][nt][r] - mn) * rs * pg[nt] + pbe[nt];
                if (OUT_BF16) {
                    float vh = __shfl_xor(v, 1);
                    if (!(l15 & 1) && node < NNODES) {
                        uint* o = (uint*)out;
                        o[(size_t)node * 64 + wn * 16 + nt * 8 + (l15 >> 1)] = pack2(v, vh);
                    }
                } else {
                    if (node < NNODES) {
                        float* o = (float*)out;
                        o[(size_t)node * 128 + nl0 + nt * 16] = v;
                    }
                }
            }
        }
    }
}

// ---------------- launch ----------------

extern "C" void kernel_launch(void* const* d_in, const int* in_sizes, int n_in,
                              void* d_out, int out_size, void* d_ws, size_t ws_size,
                              hipStream_t stream) {
    (void)in_sizes; (void)n_in; (void)out_size; (void)ws_size;

    const int*   edges = (const int*)d_in[0];
    const float* xemb  = (const float*)d_in[1];
    const float* W1  = (const float*)d_in[2];
    const float* b1  = (const float*)d_in[3];
    const float* Ws1 = (const float*)d_in[4];
    const float* bs1 = (const float*)d_in[5];
    const float* g1  = (const float*)d_in[6];
    const float* be1 = (const float*)d_in[7];
    const float* W2  = (const float*)d_in[8];
    const float* b2  = (const float*)d_in[9];
    const float* Ws2 = (const float*)d_in[10];
    const float* bs2 = (const float*)d_in[11];
    const float* g2  = (const float*)d_in[12];
    const float* be2 = (const float*)d_in[13];

    char* ws = (char*)d_ws;
    auto take = [&](size_t bytes) {
        char* p = ws;
        ws += (bytes + 255) & ~(size_t)255;
        return p;
    };
    int*    cnt    = (int*)take((size_t)NPAD * 4);
    int*    elist  = (int*)take((size_t)NPAD * CAP * 4);
    float4* cnts   = (float4*)take((size_t)NPAD * 16);
    uint*   xb0    = (uint*)take((size_t)NPAD * 128 * 2);
    uint*   xb1    = (uint*)take((size_t)NPAD * 128 * 2);
    uint*   Ab     = (uint*)take((size_t)NPAD * 384 * 2);
    uint*   Wb1    = (uint*)take((size_t)128 * 512 * 2);
    uint*   Wb2    = (uint*)take((size_t)128 * 512 * 2);
    int*    runcnt = (int*)take((size_t)NBLK_A * NBKT * 4);
    uint*   binned = (uint*)take((size_t)NBKT * NBLK_A * RUNCAP * 4);

    binfill_kernel<<<NBLK_A, 256, 0, stream>>>(edges, runcnt, binned);
    scatter_kernel<<<NBKT, 256, 0, stream>>>(binned, runcnt, cnt, elist);

    convx_kernel<<<(NNODES * 64) / 256, 256, 0, stream>>>(xemb, xb0);
    wconv_kernel<<<128, 256, 0, stream>>>(W1, Ws1, Wb1);
    wconv_kernel<<<128, 256, 0, stream>>>(W2, Ws2, Wb2);

    gather_kernel<<<NNODES / 4, 256, 0, stream>>>(xb0, cnt, elist, Ab, cnts);
    gemm_kernel<true><<<NPAD / 64, 256, 0, stream>>>(
        (const ushort*)Ab, (const ushort*)xb0, (const ushort*)Wb1,
        b1, bs1, g1, be1, cnts, xb1);

    gather_kernel<<<NNODES / 4, 256, 0, stream>>>(xb1, cnt, elist, Ab, cnts);
    gemm_kernel<false><<<NPAD / 64, 256, 0, stream>>>(
        (const ushort*)Ab, (const ushort*)xb1, (const ushort*)Wb2,
        b2, bs2, g2, be2, cnts, d_out);
}